// Round 8
// baseline (155.267 us; speedup 1.0000x reference)
//
#include <hip/hip_runtime.h>
#include <hip/hip_bf16.h>
#include <cstdint>

// Problem constants (B=16, N=4096, D_IN=D_OUT=64)
#define NB   16
#define NN   4096
#define ND   64
#define NJ   1024   // NB*ND columns of the big GEMM

typedef __attribute__((ext_vector_type(8))) short  short8;  // 8 bf16 = 4 VGPRs
typedef __attribute__((ext_vector_type(4))) float  f32x4;

__device__ __forceinline__ unsigned short f2bf(float f) {
  union { float f; unsigned int u; } v; v.f = f;
  unsigned int u = v.u;
  unsigned int r = u + 0x7FFFu + ((u >> 16) & 1u);  // round-to-nearest-even
  return (unsigned short)(r >> 16);
}
__device__ __forceinline__ float bf2f(unsigned short h) {
  union { unsigned int u; float f; } v; v.u = ((unsigned int)h) << 16; return v.f;
}

// ---------------- K1: merged prep = {Yt = (Z W)^T} + {A fp32->bf16 convert} --------
// zw blocks FIRST (bx < 1024): latency-bound, hides under the BW-bound convert
// stream (round-5 verified).
__global__ void k_prep(const float* __restrict__ A, const float* __restrict__ Z,
                       const float* __restrict__ W, unsigned short* __restrict__ Ab,
                       unsigned short* __restrict__ Yt) {
  __shared__ float zs[64 * 65];                      // 16.25 KiB (zw blocks only)
  int bx = blockIdx.x;
  int tid = threadIdx.x;
  if (bx < 1024) {
    int b  = bx >> 6;                  // [0,16)
    int m0 = (bx & 63) << 6;           // [0,4096) step 64
    const float* zb = Z + ((size_t)b * NN + m0) * ND;
#pragma unroll
    for (int r = 0; r < 4; ++r) {
      int row = r * 16 + (tid >> 4);
      int col = (tid & 15) * 4;
      float4 v = *(const float4*)(zb + (size_t)row * ND + col);
      float* d = &zs[row * 65 + col];
      d[0] = v.x; d[1] = v.y; d[2] = v.z; d[3] = v.w;   // 2 lanes/bank, free
    }
    __syncthreads();
    int lane = tid & 63;                               // = m-row within tile
    int e0 = __builtin_amdgcn_readfirstlane((tid >> 6) << 4);  // wave-uniform -> s_load W
    int m  = m0 + lane;
    float acc[16];
#pragma unroll
    for (int i = 0; i < 16; ++i) acc[i] = 0.f;
#pragma unroll
    for (int d = 0; d < 64; ++d) {
      float zd = zs[lane * 65 + d];                    // bank (lane+d)&31: free
#pragma unroll
      for (int i = 0; i < 16; ++i) acc[i] += zd * W[d * 64 + e0 + i];  // uniform -> SMEM
    }
#pragma unroll
    for (int i = 0; i < 16; ++i)
      Yt[(size_t)(b * 64 + e0 + i) * NN + m] = f2bf(acc[i]);
  } else {
    int idx = (bx - 1024) * 256 + tid;               // 2,097,152 threads exactly
    const float4* p = (const float4*)A + (size_t)idx * 2;
    float4 a = p[0], b = p[1];
    unsigned int w0 = (unsigned int)f2bf(a.x) | ((unsigned int)f2bf(a.y) << 16);
    unsigned int w1 = (unsigned int)f2bf(a.z) | ((unsigned int)f2bf(a.w) << 16);
    unsigned int w2 = (unsigned int)f2bf(b.x) | ((unsigned int)f2bf(b.y) << 16);
    unsigned int w3 = (unsigned int)f2bf(b.z) | ((unsigned int)f2bf(b.w) << 16);
    uint4 o; o.x = w0; o.y = w1; o.z = w2; o.w = w3;
    ((uint4*)Ab)[idx] = o;                           // 16B store
  }
}

// ---------------- K2: 128x128-tile GEMM, 2 blocks/CU, split-K x2 --------------------
// Round-7 delta (resubmitted after infra timeout): same verified schedule discipline
// (chunk-XOR swizzle, counted vmcnt(4), dist-1 A / dist-2 B double-buffering,
// 2-barrier phases, setprio), re-parameterized: BM=BN=128, BK=64 (row width 64
// shorts -> swizzle identical), 4 waves (2x2, per-wave 64x64), grid 512 = 2
// blocks/CU (LDS 64 KiB/block), 32 K-tiles/block. Theory: 1-block/CU barrier-
// lockstep leaves ~50% convoy stalls (MfmaUtil 31%); co-resident second block
// fills them (m114/m97 mechanism), and 2x K-depth amortizes ramp/epilogue.
__device__ __forceinline__ void gl2lds16(const unsigned short* g, unsigned short* l) {
  __builtin_amdgcn_global_load_lds(
      (const __attribute__((address_space(1))) unsigned int*)g,
      (__attribute__((address_space(3))) unsigned int*)l, 16, 0, 0);
}

#define STAGE4(GP, LP) \
  gl2lds16((GP) + srcO[0], (LP) + dstO[0]); \
  gl2lds16((GP) + srcO[1], (LP) + dstO[1]); \
  gl2lds16((GP) + srcO[2], (LP) + dstO[2]); \
  gl2lds16((GP) + srcO[3], (LP) + dstO[3]);

#define READ_A(I0) \
  afr[0][0] = *(const short8*)&lds[pA + (I0) * 1024 + c0]; \
  afr[0][1] = *(const short8*)&lds[pA + (I0) * 1024 + c1]; \
  afr[1][0] = *(const short8*)&lds[pA + ((I0) + 1) * 1024 + c0]; \
  afr[1][1] = *(const short8*)&lds[pA + ((I0) + 1) * 1024 + c1];

#define MFMA_Q(I0) \
  _Pragma("unroll") \
  for (int jj = 0; jj < 4; ++jj) { \
    acc[(I0)][jj]     = __builtin_amdgcn_mfma_f32_16x16x32_bf16(afr[0][0], bfr[jj][0], acc[(I0)][jj], 0, 0, 0); \
    acc[(I0)][jj]     = __builtin_amdgcn_mfma_f32_16x16x32_bf16(afr[0][1], bfr[jj][1], acc[(I0)][jj], 0, 0, 0); \
    acc[(I0) + 1][jj] = __builtin_amdgcn_mfma_f32_16x16x32_bf16(afr[1][0], bfr[jj][0], acc[(I0) + 1][jj], 0, 0, 0); \
    acc[(I0) + 1][jj] = __builtin_amdgcn_mfma_f32_16x16x32_bf16(afr[1][1], bfr[jj][1], acc[(I0) + 1][jj], 0, 0, 0); \
  }

#define PHASE_MFMA(I0) \
  __builtin_amdgcn_s_barrier(); \
  asm volatile("" ::: "memory"); /* compiler fence; HW waits are data-dep lgkmcnt(N) */ \
  __builtin_amdgcn_s_setprio(1); \
  MFMA_Q(I0) \
  __builtin_amdgcn_s_setprio(0); \
  __builtin_amdgcn_s_barrier();

__launch_bounds__(256, 2)  // 4 waves/block, 2 blocks/CU (2x64 KiB LDS)
__global__ void k_gemm(const unsigned short* __restrict__ Ab,
                       const unsigned short* __restrict__ Yt,
                       unsigned short* __restrict__ Pb) {
  __shared__ unsigned short lds[32768];  // 64 KiB: A dbuf 2x16KB @0, B dbuf @16384
  const int tid = threadIdx.x;
  const int w = tid >> 6, lane = tid & 63;
  const int quad = lane >> 4, l15 = lane & 15;
  const int wr = w >> 1, wc = w & 1;           // 2x2 waves, per-wave 64x64

  // XCD swizzle: bx&7 = XCD; per XCD 64 blocks = 4 m_blks x 8 j x 2 kc (j fastest:
  // 8 j-blocks + 2 kc share each 1-MiB A strip in L2).
  const int x  = blockIdx.x & 7;
  const int t9 = blockIdx.x >> 3;              // [0,64)
  const int j_blk = t9 & 7;
  const int kc    = (t9 >> 3) & 1;
  const int m_blk = x * 4 + (t9 >> 4);         // [0,32)
  const int mrow0 = m_blk << 7, jcol0 = j_blk << 7, kbase = kc << 11;

  const unsigned short* Ag = Ab + (size_t)mrow0 * 4096 + kbase;
  const unsigned short* Bg = Yt + (size_t)jcol0 * 4096 + kbase;

  // Staging (chunk-XOR, identical formula: 64-short rows = 8 chunks/row):
  // round r slot s = r*256+tid -> row = s>>3 in [0,128), kg = (s&7)^(row&7).
  int srcO[4], dstO[4];
#pragma unroll
  for (int r = 0; r < 4; ++r) {
    int s = r * 256 + tid, row = s >> 3, kg = (s & 7) ^ (row & 7);
    srcO[r] = row * 4096 + kg * 8;
    dstO[r] = (r * 256 + w * 64) * 8;          // wave-uniform LDS base (shorts)
  }

  // ds_read chunk offsets: fragment rows have row&7 == l15&7 -> conflict-free.
  const int c0 = (quad ^ (l15 & 7)) * 8;
  const int c1 = ((4 + quad) ^ (l15 & 7)) * 8;
  const int aB = (wr * 64 + l15) * 64;         // + p*8192 + i*1024 + c{0,1}
  const int bB = 16384 + (wc * 64 + l15) * 64; // + p*8192 + j*1024 + c{0,1}

  f32x4 acc[4][4];
#pragma unroll
  for (int i = 0; i < 4; ++i)
#pragma unroll
    for (int j = 0; j < 4; ++j) acc[i][j] = (f32x4){0.f, 0.f, 0.f, 0.f};

  // Prologue: A(0)->Abuf0, B(0)->Bbuf0, B(1)->Bbuf1 (12 loads).
  // vmcnt(4): tile0's 8 oldest landed; B(1) still in flight. A(1) staged at t=0 ph1.
  STAGE4(Ag, lds)
  STAGE4(Bg, lds + 16384)
  STAGE4(Bg + 64, lds + 24576)
  asm volatile("s_waitcnt vmcnt(4)" ::: "memory");
  __builtin_amdgcn_s_barrier();

  for (int t = 0; t < 32; ++t) {
    const int p = t & 1;
    const int pA = p * 8192 + aB;
    const int pB = p * 8192 + bB;
    short8 bfr[4][2], afr[2][2];

    // ---- phase 1: all B-frags + A i0-1; stage A(t+1) -> A-buf p^1 ----
#pragma unroll
    for (int j = 0; j < 4; ++j) {
      bfr[j][0] = *(const short8*)&lds[pB + j * 1024 + c0];
      bfr[j][1] = *(const short8*)&lds[pB + j * 1024 + c1];
    }
    READ_A(0)
    if (t < 31) {
      const unsigned short* g = Ag + (t + 1) * 64;
      unsigned short* lb = lds + (p ^ 1) * 8192;
      STAGE4(g, lb)
    }
    asm volatile("s_waitcnt lgkmcnt(8)" ::: "memory");  // 12 ds_reads this phase
    PHASE_MFMA(0)

    // ---- phase 2: A i2-3 (bfr live in regs); stage B(t+2) -> B-buf p (read in
    //      ph1, write-after-read separated by ph1's trailing barrier);
    //      counted vmcnt once per K-tile: 12 in flight, drain oldest 8 = tile t+1 ----
    READ_A(2)
    if (t < 30) {
      const unsigned short* g = Bg + (t + 2) * 64;
      unsigned short* lb = lds + 16384 + p * 8192;
      STAGE4(g, lb)
    }
    if (t < 30)      { asm volatile("s_waitcnt vmcnt(4)" ::: "memory"); }
    else if (t == 30){ asm volatile("s_waitcnt vmcnt(0)" ::: "memory"); }
    PHASE_MFMA(2)
  }

  // Epilogue: C/D layout col=l15, row=quad*4+rg (m89/m91-verified mapping).
  unsigned short* P = Pb + (size_t)kc * ((size_t)NN * NJ);
  const int r0base = mrow0 + wr * 64;
  const int cb = jcol0 + wc * 64;
#pragma unroll
  for (int i = 0; i < 4; ++i) {
    const int r0 = r0base + i * 16 + quad * 4;
#pragma unroll
    for (int j = 0; j < 4; ++j) {
      const int jc = cb + j * 16 + l15;
      unsigned short* pp = P + (size_t)r0 * NJ + jc;
#pragma unroll
      for (int rg = 0; rg < 4; ++rg)
        pp[(size_t)rg * NJ] = f2bf(acc[i][j][rg]);
    }
  }
}

// ---------------- K3: out[m-major] = sum_kc P[kc] (x2 now); 8 floats/thread ---------
__global__ void k_reduce(const unsigned short* __restrict__ P, float* __restrict__ out) {
  int t = blockIdx.x * 256 + threadIdx.x;      // 524,288 threads exactly
  size_t of = (size_t)t * 8;                   // out flat index (8 consecutive floats)
  int bidx = t >> 15;                          // of >> 18
  int rem  = (int)(of & 262143);               // within one batch: m*64 + e
  int m = rem >> 6, e = rem & 63;
  size_t pj = (size_t)m * NJ + bidx * 64 + e;  // P row-index: [m][j= bidx*64+e]
  float s[8];
#pragma unroll
  for (int u = 0; u < 8; ++u) s[u] = 0.f;
#pragma unroll
  for (int kc = 0; kc < 2; ++kc) {
    short8 v = *(const short8*)(P + (size_t)kc * (NN * NJ) + pj);  // 16B load
#pragma unroll
    for (int u = 0; u < 8; ++u) s[u] += bf2f((unsigned short)v[u]);
  }
  float4 o0 = {s[0], s[1], s[2], s[3]}, o1 = {s[4], s[5], s[6], s[7]};
  ((float4*)(out + of))[0] = o0;
  ((float4*)(out + of))[1] = o1;
}

extern "C" void kernel_launch(void* const* d_in, const int* in_sizes, int n_in,
                              void* d_out, int out_size, void* d_ws, size_t ws_size,
                              hipStream_t stream) {
  const float* Z = (const float*)d_in[0];   // [16][4096][64] fp32
  const float* A = (const float*)d_in[1];   // [4096][4096] fp32
  const float* W = (const float*)d_in[2];   // [64][64] fp32
  float* out = (float*)d_out;               // [16][4096][64] fp32

  unsigned short* Ab = (unsigned short*)d_ws;                                     // 32 MiB bf16 A
  unsigned short* Yt = (unsigned short*)((char*)d_ws + (size_t)32 * 1024 * 1024); // 8 MiB bf16 Y^T
  unsigned short* Pb = (unsigned short*)((char*)d_ws + (size_t)40 * 1024 * 1024); // 16 MiB bf16 partials x2

  k_prep<<<9216, 256, 0, stream>>>(A, Z, W, Ab, Yt);
  k_gemm<<<512, 256, 0, stream>>>(Ab, Yt, Pb);
  k_reduce<<<2048, 256, 0, stream>>>(Pb, out);
}